// Round 4
// baseline (87.407 us; speedup 1.0000x reference)
//
#include <hip/hip_runtime.h>
#include <stdint.h>

// NormalizedLoss: batched chamfer + coverage/quality on point clouds.
// x: [32, 2048, 3] fp32, y: [32, 2048, 3] fp32 -> out: [val, cd, cov, qual] fp32.
//
// R19: attack nn's LDS-return-bandwidth bound. A wave-uniform ds_read_b128
// still moves 16B x 64 lanes = 1024B through the 128B/cyc LDS port (~8-12
// cyc); at P=4 that's 4096 b128/CU ~= 14-20us -- the dominant nn component
// (VALU floor is 10.3us, nn measured ~29). P=8: each record read now feeds
// 8 p-points per lane -> half the LDS reads chip-wide, same VALU total.
// Geometry: 512 blocks (side|b|pc(2)|qc) x 512 thr, block = 512p x 1024q,
// launch_bounds(512,4) (<=128 VGPR, 16 waves/CU, 2 blocks/CU).
// part layout + merge3 + all math bit-identical to R18 (85.7us).
//
// Inner loop per record: 2x ds_read_b128 (uniform) + 8 x {3 v_pk_fma_f32 +
// 2 v_bfi_b32 + 1 v_min3_f32}; 11-bit q-index embedded in the distance
// mantissa -> single float carries (d, argmin) lex order. Truncation ~1e-3
// << 1.2e-2 threshold.

#define BB 32
#define NP 2048
#define BIGF 1e10f

typedef unsigned int u32;
typedef float f2 __attribute__((ext_vector_type(2)));

__device__ __forceinline__ f2 pk_fma(f2 a, f2 b, f2 c) {
  f2 d;
  asm("v_pk_fma_f32 %0, %1, %2, %3" : "=v"(d) : "v"(a), "v"(b), "v"(c));
  return d;
}
__device__ __forceinline__ float min3(float a, float b, float c) {
  float r;
  asm("v_min3_f32 %0, %1, %2, %3" : "=v"(r) : "v"(a), "v"(b), "v"(c));
  return r;
}
// (maskv & d) | (~maskv & jg) with maskv=0xFFFFF800 -> embed jg in low 11 bits
__device__ __forceinline__ float emb(float d, u32 jg, u32 maskv) {
  float r;
  asm("v_bfi_b32 %0, %1, %2, %3" : "=v"(r) : "v"(maskv), "v"(d), "s"(jg));
  return r;
}

__global__ __launch_bounds__(512, 4) void nn_kernel(const float* __restrict__ x,
                                                    const float* __restrict__ y,
                                                    u32* __restrict__ part,
                                                    float* __restrict__ out) {
  int bid = blockIdx.x;  // 512 blocks: side(1)|b(5)|pc(2)|qc(1)
  int side = bid >> 8;
  int b = (bid >> 3) & 31;
  int pc = (bid >> 1) & 3;
  int qc = bid & 1;
  int tid = threadIdx.x;
  int w = __builtin_amdgcn_readfirstlane(tid >> 6);  // 0..7, wave-uniform
  int lane = tid & 63;

  // zero the output accumulators (merge3 atomicAdds into them; stream order
  // + kernel-end writeback makes this visible to merge3's atomics)
  if (bid == 0 && tid < 4) out[tid] = 0.f;

  __shared__ float4 qs[1024];     // 16KB; rec r -> qs[2r]=(x0,x1,y0,y1), qs[2r+1]=(z0,z1,n0,n1)
  __shared__ u32 merged[8][512];  // 16KB per-wave embedded (d|idx) partials

  // ---- stage this block's 1024 q (qc half); 2 points per thread ----
  {
    const float* qraw = (side ? x : y) + (b * NP + qc * 1024) * 3 + tid * 6;
    f2 a01 = *(const f2*)(qraw);      // x0,y0
    f2 a23 = *(const f2*)(qraw + 2);  // z0,x1
    f2 a45 = *(const f2*)(qraw + 4);  // y1,z1
    float q0x = a01.x, q0y = a01.y, q0z = a23.x;
    float q1x = a23.y, q1y = a45.x, q1z = a45.y;
    float n0 = q0x * q0x + q0y * q0y + q0z * q0z;
    float n1 = q1x * q1x + q1y * q1y + q1z * q1z;
    if (q0x + q0y + q0z == 0.f) n0 += BIGF;  // invalid rows out of every min
    if (q1x + q1y + q1z == 0.f) n1 += BIGF;
    qs[2 * tid]     = make_float4(q0x, q1x, q0y, q1y);
    qs[2 * tid + 1] = make_float4(q0z, q1z, n0, n1);
  }

  // ---- p prologue: every wave loads the SAME 512 p; -2p dup'd into f2 ----
  const float* praw = (side ? y : x) + (b * NP + pc * 512) * 3;
  f2 pmx[8], pmy[8], pmz[8];
  float best[8];
#pragma unroll
  for (int k = 0; k < 8; ++k) {
    int pl = lane + 64 * k;
    float p0 = praw[3 * pl], p1 = praw[3 * pl + 1], p2 = praw[3 * pl + 2];
    pmx[k] = (f2){-2.f * p0, -2.f * p0};
    pmy[k] = (f2){-2.f * p1, -2.f * p1};
    pmz[k] = (f2){-2.f * p2, -2.f * p2};
    best[k] = 3.0e38f;
  }
  __syncthreads();

  // ---- inner loop: wave's 64 records (128 q) vs its 8 p-points ----
  const float4* qr = &qs[w * 128];
  u32 je = (u32)(qc * 1024 + w * 128);  // global q index of this wave's rec 0
  const u32 mv = 0xFFFFF800u;           // loop-invariant embed mask (VGPR)
#pragma unroll 4
  for (int r = 0; r < 64; ++r) {
    float4 A = qr[2 * r];      // wave-uniform ds_read_b128 (broadcast)
    float4 B = qr[2 * r + 1];
    f2 qx2 = (f2){A.x, A.y};
    f2 qy2 = (f2){A.z, A.w};
    f2 qz2 = (f2){B.x, B.y};
    f2 qw2 = (f2){B.z, B.w};
    u32 jg = je + 2 * (u32)r, jg1 = jg + 1;  // wave-uniform (SGPR, scalar pipe)
#pragma unroll
    for (int k = 0; k < 8; ++k) {
      f2 d2 = pk_fma(qx2, pmx[k], pk_fma(qy2, pmy[k], pk_fma(qz2, pmz[k], qw2)));
      best[k] = min3(best[k], emb(d2.x, jg, mv), emb(d2.y, jg1, mv));
    }
  }

#pragma unroll
  for (int k = 0; k < 8; ++k) merged[w][lane + 64 * k] = __float_as_uint(best[k]);
  __syncthreads();

  // ---- merge 8 wave partials; store embedded u32 per p (512/block) ----
  {
    float bd = __uint_as_float(merged[0][tid]);
#pragma unroll
    for (int ww = 1; ww < 8; ++ww) bd = fminf(bd, __uint_as_float(merged[ww][tid]));
    // part[qc][side*65536 + b*2048 + pc*512 + tid]
    part[qc * 131072 + side * 65536 + b * 2048 + pc * 512 + tid] = __float_as_uint(bd);
  }
}

// 64 blocks x 1024 thr: one block per (side,b). Combine qc halves, recompute
// p-norm/validity, build the (block-local) 2048-bit q hit bitmask in LDS,
// count valid q, then atomicAdd the closed-form per-(side,b) contribution
// into out[]. Linearity of all four outputs over (side,b) terms makes this
// exact (modulo fp-add order, ~1e-7):
//   out[1] cd   += (ss/n_p)/32            (both sides)
//   out[2] cov  += (hits/n_q)/32          (side 0: p=x, q=y)
//   out[3] qual += (hits/n_q)/32          (side 1: p=y, q=x)
//   out[0] val  += (ss/n_p - 1e-4*hits/n_q)/32
__global__ __launch_bounds__(1024) void merge3_kernel(const float* __restrict__ x,
                                                      const float* __restrict__ y,
                                                      const u32* __restrict__ part,
                                                      float* __restrict__ out) {
  int bid = blockIdx.x;  // 64: side(1)|b(5)
  int side = bid >> 5;
  int b = bid & 31;
  int tid = threadIdx.x;
  int lane = tid & 63, w = tid >> 6;  // 16 waves

  __shared__ u32 hitlds[64];          // 2048-bit q hit bitmask
  __shared__ float redc[16], redn[16], redq[16];
  if (tid < 64) hitlds[tid] = 0u;
  __syncthreads();

  const float* praw = (side ? y : x) + b * NP * 3;
  const float* qraw = (side ? x : y) + b * NP * 3;

  float contrib = 0.f, cnt = 0.f, qcnt = 0.f;
#pragma unroll
  for (int k = 0; k < 2; ++k) {
    int pi = tid + k * 1024;
    int pidx = side * 65536 + b * 2048 + pi;
    float bd = fminf(__uint_as_float(part[pidx]), __uint_as_float(part[131072 + pidx]));
    u32 bits = __float_as_uint(bd);
    u32 bi = bits & 0x7FFu;                            // global q index
    float dmin = __uint_as_float(bits & 0xFFFFF800u);  // truncated min d'
    float p0 = praw[3 * pi], p1 = praw[3 * pi + 1], p2 = praw[3 * pi + 2];
    if (p0 + p1 + p2 != 0.f) {
      contrib += dmin + p0 * p0 + p1 * p1 + p2 * p2;
      cnt += 1.f;
      atomicOr(&hitlds[bi >> 5], 1u << (bi & 31));
    }
    float q0 = qraw[3 * pi], q1 = qraw[3 * pi + 1], q2 = qraw[3 * pi + 2];
    if (q0 + q1 + q2 != 0.f) qcnt += 1.f;
  }

  for (int o = 32; o > 0; o >>= 1) {
    contrib += __shfl_down(contrib, o, 64);
    cnt += __shfl_down(cnt, o, 64);
    qcnt += __shfl_down(qcnt, o, 64);
  }
  if (lane == 0) { redc[w] = contrib; redn[w] = cnt; redq[w] = qcnt; }
  __syncthreads();

  if (tid < 64) {  // wave 0: popcount bitmask + final combine
    float h = (float)__popc(hitlds[tid]);
    for (int o = 32; o > 0; o >>= 1) h += __shfl_down(h, o, 64);
    if (tid == 0) {
      float s = 0.f, n = 0.f, nq = 0.f;
#pragma unroll
      for (int i = 0; i < 16; ++i) { s += redc[i]; n += redn[i]; nq += redq[i]; }
      float cdt = s / n;       // this side's mean-min-distance term
      float hqt = h / nq;      // hit fraction of q indices
      const float inv = 1.f / (float)BB;
      atomicAdd(out + 1, cdt * inv);
      atomicAdd(out + 2 + side, hqt * inv);
      atomicAdd(out + 0, (cdt - 1e-4f * hqt) * inv);
    }
  }
}

extern "C" void kernel_launch(void* const* d_in, const int* in_sizes, int n_in,
                              void* d_out, int out_size, void* d_ws, size_t ws_size,
                              hipStream_t stream) {
  const float* x = (const float*)d_in[0];
  const float* y = (const float*)d_in[1];
  float* out = (float*)d_out;
  char* ws = (char*)d_ws;

  // ws layout: [0, 1MB) part: 2 qc x 131072 u32 embedded (d|idx).
  // Fully written by nn_kernel before merge3 reads it; no memset needed.
  u32* part = (u32*)ws;

  nn_kernel<<<512, 512, 0, stream>>>(x, y, part, out);
  merge3_kernel<<<64, 1024, 0, stream>>>(x, y, part, out);
}

// Round 5
// 84.366 us; speedup vs baseline: 1.0360x; 1.0360x over previous
//
#include <hip/hip_runtime.h>
#include <stdint.h>

// NormalizedLoss: batched chamfer + coverage/quality on point clouds.
// x: [32, 2048, 3] fp32, y: [32, 2048, 3] fp32 -> out: [val, cd, cov, qual] fp32.
//
// R20: R18 base (P=4, 1024x512, bfi embed; 85.7us measured) + ring-3
// register prefetch of q-records. R19 falsified the LDS-BW theory (P=8 with
// half the reads regressed) -> uniform ds_read_b128 is a broadcast; the ~17us
// of nn stall must be per-unroll-body lgkmcnt ramp (reads issued at body top,
// first use waits full ~120cyc LDS latency; no cross-backedge pipelining).
// Ring-3: issue record r+3's ds_read during record r's compute (144cyc in
// flight >= 120 latency -> structurally zero stall). Full unroll keeps ring
// indices compile-time (no scratch). +32 VGPR -> launch_bounds(512,4)
// (<=128 VGPR, 16 waves/CU); issue port still saturated (ILP-4, no bubbles).
//
// nn: 1024 blocks (side|b|pc(3)|qc(1)) x 512 thr, P=4 per lane, q staged in
// LDS as pair-records, 8-wave q-split. Inner: 3 v_pk_fma_f32 + 2 v_bfi_b32 +
// 1 v_min3_f32 per k; 11-bit q-index embedded in the distance mantissa ->
// single float carries (d, argmin) lex order. Truncation ~1e-3 << 1.2e-2.

#define BB 32
#define NP 2048
#define BIGF 1e10f

typedef unsigned int u32;
typedef float f2 __attribute__((ext_vector_type(2)));

__device__ __forceinline__ f2 pk_fma(f2 a, f2 b, f2 c) {
  f2 d;
  asm("v_pk_fma_f32 %0, %1, %2, %3" : "=v"(d) : "v"(a), "v"(b), "v"(c));
  return d;
}
__device__ __forceinline__ float min3(float a, float b, float c) {
  float r;
  asm("v_min3_f32 %0, %1, %2, %3" : "=v"(r) : "v"(a), "v"(b), "v"(c));
  return r;
}
// (maskv & d) | (~maskv & jg) with maskv=0xFFFFF800 -> embed jg in low 11 bits
__device__ __forceinline__ float emb(float d, u32 jg, u32 maskv) {
  float r;
  asm("v_bfi_b32 %0, %1, %2, %3" : "=v"(r) : "v"(maskv), "v"(d), "s"(jg));
  return r;
}

__global__ __launch_bounds__(512, 4) void nn_kernel(const float* __restrict__ x,
                                                    const float* __restrict__ y,
                                                    u32* __restrict__ part,
                                                    float* __restrict__ out) {
  int bid = blockIdx.x;  // 1024 blocks: side(1)|b(5)|pc(3)|qc(1)
  int side = bid >> 9;
  int b = (bid >> 4) & 31;
  int pc = (bid >> 1) & 7;
  int qc = bid & 1;
  int tid = threadIdx.x;
  int w = __builtin_amdgcn_readfirstlane(tid >> 6);  // 0..7, wave-uniform
  int lane = tid & 63;

  // zero the output accumulators (merge3 atomicAdds into them; stream order
  // + kernel-end writeback makes this visible to merge3's atomics)
  if (bid == 0 && tid < 4) out[tid] = 0.f;

  __shared__ float4 qs[1024];     // 16KB; rec r -> qs[2r]=(x0,x1,y0,y1), qs[2r+1]=(z0,z1,n0,n1)
  __shared__ u32 merged[8][256];  // 8KB per-wave embedded (d|idx) partials

  // ---- stage this block's 1024 q (qc half); 2 points per thread ----
  {
    const float* qraw = (side ? x : y) + (b * NP + qc * 1024) * 3 + tid * 6;
    f2 a01 = *(const f2*)(qraw);      // x0,y0
    f2 a23 = *(const f2*)(qraw + 2);  // z0,x1
    f2 a45 = *(const f2*)(qraw + 4);  // y1,z1
    float q0x = a01.x, q0y = a01.y, q0z = a23.x;
    float q1x = a23.y, q1y = a45.x, q1z = a45.y;
    float n0 = q0x * q0x + q0y * q0y + q0z * q0z;
    float n1 = q1x * q1x + q1y * q1y + q1z * q1z;
    if (q0x + q0y + q0z == 0.f) n0 += BIGF;  // invalid rows out of every min
    if (q1x + q1y + q1z == 0.f) n1 += BIGF;
    qs[2 * tid]     = make_float4(q0x, q1x, q0y, q1y);
    qs[2 * tid + 1] = make_float4(q0z, q1z, n0, n1);
  }

  // ---- p prologue: every wave loads the SAME 256 p; -2p dup'd into f2 ----
  const float* praw = (side ? y : x) + (b * NP + pc * 256) * 3;
  f2 pmx[4], pmy[4], pmz[4];
  float best[4];
#pragma unroll
  for (int k = 0; k < 4; ++k) {
    int pl = lane + 64 * k;
    float p0 = praw[3 * pl], p1 = praw[3 * pl + 1], p2 = praw[3 * pl + 2];
    pmx[k] = (f2){-2.f * p0, -2.f * p0};
    pmy[k] = (f2){-2.f * p1, -2.f * p1};
    pmz[k] = (f2){-2.f * p2, -2.f * p2};
    best[k] = 3.0e38f;
  }
  __syncthreads();

  // ---- inner loop: wave's 64 records (128 q) vs its 4 p-points ----
  // ring-3 register prefetch: record r+3's ds_read issues during record r's
  // compute (~144 cyc in flight >= ~120 cyc LDS latency -> no lgkm stall).
  const float4* qr = &qs[w * 128];
  u32 je = (u32)(qc * 1024 + w * 128);  // global q index of this wave's rec 0
  const u32 mv = 0xFFFFF800u;           // loop-invariant embed mask (VGPR)

  float4 Ar[4], Br[4];
  Ar[0] = qr[0]; Br[0] = qr[1];
  Ar[1] = qr[2]; Br[1] = qr[3];
  Ar[2] = qr[4]; Br[2] = qr[5];
#pragma unroll
  for (int r = 0; r < 64; ++r) {
    if (r + 3 < 64) {                      // compile-time pruned after unroll
      Ar[(r + 3) & 3] = qr[2 * (r + 3)];
      Br[(r + 3) & 3] = qr[2 * (r + 3) + 1];
    }
    float4 A = Ar[r & 3];                  // static index (full unroll)
    float4 B = Br[r & 3];
    f2 qx2 = (f2){A.x, A.y};
    f2 qy2 = (f2){A.z, A.w};
    f2 qz2 = (f2){B.x, B.y};
    f2 qw2 = (f2){B.z, B.w};
    u32 jg = je + 2 * (u32)r, jg1 = jg + 1;  // wave-uniform (SGPR, scalar pipe)
#pragma unroll
    for (int k = 0; k < 4; ++k) {
      f2 d2 = pk_fma(qx2, pmx[k], pk_fma(qy2, pmy[k], pk_fma(qz2, pmz[k], qw2)));
      best[k] = min3(best[k], emb(d2.x, jg, mv), emb(d2.y, jg1, mv));
    }
  }

  merged[w][lane +   0] = __float_as_uint(best[0]);
  merged[w][lane +  64] = __float_as_uint(best[1]);
  merged[w][lane + 128] = __float_as_uint(best[2]);
  merged[w][lane + 192] = __float_as_uint(best[3]);
  __syncthreads();

  // ---- merge 8 wave partials; store embedded u32 per p ----
  if (tid < 256) {
    float bd = __uint_as_float(merged[0][tid]);
#pragma unroll
    for (int ww = 1; ww < 8; ++ww) bd = fminf(bd, __uint_as_float(merged[ww][tid]));
    // part[qc][side*65536 + b*2048 + pc*256 + tid]
    part[qc * 131072 + side * 65536 + b * 2048 + pc * 256 + tid] = __float_as_uint(bd);
  }
}

// 64 blocks x 1024 thr: one block per (side,b). Combine qc halves, recompute
// p-norm/validity, build the (block-local) 2048-bit q hit bitmask in LDS,
// count valid q, then atomicAdd the closed-form per-(side,b) contribution
// into out[]. Linearity of all four outputs over (side,b) terms makes this
// exact (modulo fp-add order, ~1e-7):
//   out[1] cd   += (ss/n_p)/32            (both sides)
//   out[2] cov  += (hits/n_q)/32          (side 0: p=x, q=y)
//   out[3] qual += (hits/n_q)/32          (side 1: p=y, q=x)
//   out[0] val  += (ss/n_p - 1e-4*hits/n_q)/32
__global__ __launch_bounds__(1024) void merge3_kernel(const float* __restrict__ x,
                                                      const float* __restrict__ y,
                                                      const u32* __restrict__ part,
                                                      float* __restrict__ out) {
  int bid = blockIdx.x;  // 64: side(1)|b(5)
  int side = bid >> 5;
  int b = bid & 31;
  int tid = threadIdx.x;
  int lane = tid & 63, w = tid >> 6;  // 16 waves

  __shared__ u32 hitlds[64];          // 2048-bit q hit bitmask
  __shared__ float redc[16], redn[16], redq[16];
  if (tid < 64) hitlds[tid] = 0u;
  __syncthreads();

  const float* praw = (side ? y : x) + b * NP * 3;
  const float* qraw = (side ? x : y) + b * NP * 3;

  float contrib = 0.f, cnt = 0.f, qcnt = 0.f;
#pragma unroll
  for (int k = 0; k < 2; ++k) {
    int pi = tid + k * 1024;
    int pidx = side * 65536 + b * 2048 + pi;
    float bd = fminf(__uint_as_float(part[pidx]), __uint_as_float(part[131072 + pidx]));
    u32 bits = __float_as_uint(bd);
    u32 bi = bits & 0x7FFu;                            // global q index
    float dmin = __uint_as_float(bits & 0xFFFFF800u);  // truncated min d'
    float p0 = praw[3 * pi], p1 = praw[3 * pi + 1], p2 = praw[3 * pi + 2];
    if (p0 + p1 + p2 != 0.f) {
      contrib += dmin + p0 * p0 + p1 * p1 + p2 * p2;
      cnt += 1.f;
      atomicOr(&hitlds[bi >> 5], 1u << (bi & 31));
    }
    float q0 = qraw[3 * pi], q1 = qraw[3 * pi + 1], q2 = qraw[3 * pi + 2];
    if (q0 + q1 + q2 != 0.f) qcnt += 1.f;
  }

  for (int o = 32; o > 0; o >>= 1) {
    contrib += __shfl_down(contrib, o, 64);
    cnt += __shfl_down(cnt, o, 64);
    qcnt += __shfl_down(qcnt, o, 64);
  }
  if (lane == 0) { redc[w] = contrib; redn[w] = cnt; redq[w] = qcnt; }
  __syncthreads();

  if (tid < 64) {  // wave 0: popcount bitmask + final combine
    float h = (float)__popc(hitlds[tid]);
    for (int o = 32; o > 0; o >>= 1) h += __shfl_down(h, o, 64);
    if (tid == 0) {
      float s = 0.f, n = 0.f, nq = 0.f;
#pragma unroll
      for (int i = 0; i < 16; ++i) { s += redc[i]; n += redn[i]; nq += redq[i]; }
      float cdt = s / n;       // this side's mean-min-distance term
      float hqt = h / nq;      // hit fraction of q indices
      const float inv = 1.f / (float)BB;
      atomicAdd(out + 1, cdt * inv);
      atomicAdd(out + 2 + side, hqt * inv);
      atomicAdd(out + 0, (cdt - 1e-4f * hqt) * inv);
    }
  }
}

extern "C" void kernel_launch(void* const* d_in, const int* in_sizes, int n_in,
                              void* d_out, int out_size, void* d_ws, size_t ws_size,
                              hipStream_t stream) {
  const float* x = (const float*)d_in[0];
  const float* y = (const float*)d_in[1];
  float* out = (float*)d_out;
  char* ws = (char*)d_ws;

  // ws layout: [0, 1MB) part: 2 qc x 131072 u32 embedded (d|idx).
  // Fully written by nn_kernel before merge3 reads it; no memset needed.
  u32* part = (u32*)ws;

  nn_kernel<<<1024, 512, 0, stream>>>(x, y, part, out);
  merge3_kernel<<<64, 1024, 0, stream>>>(x, y, part, out);
}

// Round 6
// 83.690 us; speedup vs baseline: 1.0444x; 1.0081x over previous
//
#include <hip/hip_runtime.h>
#include <stdint.h>

// NormalizedLoss: batched chamfer + coverage/quality on point clouds.
// x: [32, 2048, 3] fp32, y: [32, 2048, 3] fp32 -> out: [val, cd, cov, qual] fp32.
//
// R21: combine R20's register-ring prefetch WITH R18's full occupancy.
// R20 decomposition: ring-3 at (512,4) = -3us prefetch gain minus ~1.7us
// occupancy loss. Ring-2 costs only +16 VGPR -> total ~56, fits the 64-VGPR
// budget of launch_bounds(512,8) = 8 waves/SIMD = 32 waves/CU. Ring-2's
// ~90cyc in-flight window covers most of the ~120cyc LDS latency; the
// residual per-record bubble is hidden by 8-wave/SIMD round-robin (which
// R20's 4-wave config lacked). Math bit-identical to R18/R20.
//
// nn: 1024 blocks (side|b|pc(3)|qc(1)) x 512 thr, P=4 per lane, q staged in
// LDS as pair-records, 8-wave q-split. Inner: 3 v_pk_fma_f32 + 2 v_bfi_b32 +
// 1 v_min3_f32 per k; 11-bit q-index embedded in the distance mantissa ->
// single float carries (d, argmin) lex order. Truncation ~1e-3 << 1.2e-2.

#define BB 32
#define NP 2048
#define BIGF 1e10f

typedef unsigned int u32;
typedef float f2 __attribute__((ext_vector_type(2)));

__device__ __forceinline__ f2 pk_fma(f2 a, f2 b, f2 c) {
  f2 d;
  asm("v_pk_fma_f32 %0, %1, %2, %3" : "=v"(d) : "v"(a), "v"(b), "v"(c));
  return d;
}
__device__ __forceinline__ float min3(float a, float b, float c) {
  float r;
  asm("v_min3_f32 %0, %1, %2, %3" : "=v"(r) : "v"(a), "v"(b), "v"(c));
  return r;
}
// (maskv & d) | (~maskv & jg) with maskv=0xFFFFF800 -> embed jg in low 11 bits
__device__ __forceinline__ float emb(float d, u32 jg, u32 maskv) {
  float r;
  asm("v_bfi_b32 %0, %1, %2, %3" : "=v"(r) : "v"(maskv), "v"(d), "s"(jg));
  return r;
}

__global__ __launch_bounds__(512, 8) void nn_kernel(const float* __restrict__ x,
                                                    const float* __restrict__ y,
                                                    u32* __restrict__ part,
                                                    float* __restrict__ out) {
  int bid = blockIdx.x;  // 1024 blocks: side(1)|b(5)|pc(3)|qc(1)
  int side = bid >> 9;
  int b = (bid >> 4) & 31;
  int pc = (bid >> 1) & 7;
  int qc = bid & 1;
  int tid = threadIdx.x;
  int w = __builtin_amdgcn_readfirstlane(tid >> 6);  // 0..7, wave-uniform
  int lane = tid & 63;

  // zero the output accumulators (merge3 atomicAdds into them; stream order
  // + kernel-end writeback makes this visible to merge3's atomics)
  if (bid == 0 && tid < 4) out[tid] = 0.f;

  __shared__ float4 qs[1024];     // 16KB; rec r -> qs[2r]=(x0,x1,y0,y1), qs[2r+1]=(z0,z1,n0,n1)
  __shared__ u32 merged[8][256];  // 8KB per-wave embedded (d|idx) partials

  // ---- stage this block's 1024 q (qc half); 2 points per thread ----
  {
    const float* qraw = (side ? x : y) + (b * NP + qc * 1024) * 3 + tid * 6;
    f2 a01 = *(const f2*)(qraw);      // x0,y0
    f2 a23 = *(const f2*)(qraw + 2);  // z0,x1
    f2 a45 = *(const f2*)(qraw + 4);  // y1,z1
    float q0x = a01.x, q0y = a01.y, q0z = a23.x;
    float q1x = a23.y, q1y = a45.x, q1z = a45.y;
    float n0 = q0x * q0x + q0y * q0y + q0z * q0z;
    float n1 = q1x * q1x + q1y * q1y + q1z * q1z;
    if (q0x + q0y + q0z == 0.f) n0 += BIGF;  // invalid rows out of every min
    if (q1x + q1y + q1z == 0.f) n1 += BIGF;
    qs[2 * tid]     = make_float4(q0x, q1x, q0y, q1y);
    qs[2 * tid + 1] = make_float4(q0z, q1z, n0, n1);
  }

  // ---- p prologue: every wave loads the SAME 256 p; -2p dup'd into f2 ----
  const float* praw = (side ? y : x) + (b * NP + pc * 256) * 3;
  f2 pmx[4], pmy[4], pmz[4];
  float best[4];
#pragma unroll
  for (int k = 0; k < 4; ++k) {
    int pl = lane + 64 * k;
    float p0 = praw[3 * pl], p1 = praw[3 * pl + 1], p2 = praw[3 * pl + 2];
    pmx[k] = (f2){-2.f * p0, -2.f * p0};
    pmy[k] = (f2){-2.f * p1, -2.f * p1};
    pmz[k] = (f2){-2.f * p2, -2.f * p2};
    best[k] = 3.0e38f;
  }
  __syncthreads();

  // ---- inner loop: wave's 64 records (128 q) vs its 4 p-points ----
  // ring-2 register prefetch (fits 64-VGPR budget of 8 waves/SIMD): record
  // r+2's ds_read issues during record r's compute; residual latency is
  // covered by cross-wave scheduling at 32 waves/CU.
  const float4* qr = &qs[w * 128];
  u32 je = (u32)(qc * 1024 + w * 128);  // global q index of this wave's rec 0
  const u32 mv = 0xFFFFF800u;           // loop-invariant embed mask (VGPR)

  float4 Ar[2], Br[2];
  Ar[0] = qr[0]; Br[0] = qr[1];
  Ar[1] = qr[2]; Br[1] = qr[3];
#pragma unroll
  for (int r = 0; r < 64; ++r) {
    float4 A = Ar[r & 1];                  // static index (full unroll)
    float4 B = Br[r & 1];
    if (r + 2 < 64) {                      // compile-time pruned after unroll
      Ar[r & 1] = qr[2 * (r + 2)];
      Br[r & 1] = qr[2 * (r + 2) + 1];
    }
    f2 qx2 = (f2){A.x, A.y};
    f2 qy2 = (f2){A.z, A.w};
    f2 qz2 = (f2){B.x, B.y};
    f2 qw2 = (f2){B.z, B.w};
    u32 jg = je + 2 * (u32)r, jg1 = jg + 1;  // wave-uniform (SGPR, scalar pipe)
#pragma unroll
    for (int k = 0; k < 4; ++k) {
      f2 d2 = pk_fma(qx2, pmx[k], pk_fma(qy2, pmy[k], pk_fma(qz2, pmz[k], qw2)));
      best[k] = min3(best[k], emb(d2.x, jg, mv), emb(d2.y, jg1, mv));
    }
  }

  merged[w][lane +   0] = __float_as_uint(best[0]);
  merged[w][lane +  64] = __float_as_uint(best[1]);
  merged[w][lane + 128] = __float_as_uint(best[2]);
  merged[w][lane + 192] = __float_as_uint(best[3]);
  __syncthreads();

  // ---- merge 8 wave partials; store embedded u32 per p ----
  if (tid < 256) {
    float bd = __uint_as_float(merged[0][tid]);
#pragma unroll
    for (int ww = 1; ww < 8; ++ww) bd = fminf(bd, __uint_as_float(merged[ww][tid]));
    // part[qc][side*65536 + b*2048 + pc*256 + tid]
    part[qc * 131072 + side * 65536 + b * 2048 + pc * 256 + tid] = __float_as_uint(bd);
  }
}

// 64 blocks x 1024 thr: one block per (side,b). Combine qc halves, recompute
// p-norm/validity, build the (block-local) 2048-bit q hit bitmask in LDS,
// count valid q, then atomicAdd the closed-form per-(side,b) contribution
// into out[]. Linearity of all four outputs over (side,b) terms makes this
// exact (modulo fp-add order, ~1e-7):
//   out[1] cd   += (ss/n_p)/32            (both sides)
//   out[2] cov  += (hits/n_q)/32          (side 0: p=x, q=y)
//   out[3] qual += (hits/n_q)/32          (side 1: p=y, q=x)
//   out[0] val  += (ss/n_p - 1e-4*hits/n_q)/32
__global__ __launch_bounds__(1024) void merge3_kernel(const float* __restrict__ x,
                                                      const float* __restrict__ y,
                                                      const u32* __restrict__ part,
                                                      float* __restrict__ out) {
  int bid = blockIdx.x;  // 64: side(1)|b(5)
  int side = bid >> 5;
  int b = bid & 31;
  int tid = threadIdx.x;
  int lane = tid & 63, w = tid >> 6;  // 16 waves

  __shared__ u32 hitlds[64];          // 2048-bit q hit bitmask
  __shared__ float redc[16], redn[16], redq[16];
  if (tid < 64) hitlds[tid] = 0u;
  __syncthreads();

  const float* praw = (side ? y : x) + b * NP * 3;
  const float* qraw = (side ? x : y) + b * NP * 3;

  float contrib = 0.f, cnt = 0.f, qcnt = 0.f;
#pragma unroll
  for (int k = 0; k < 2; ++k) {
    int pi = tid + k * 1024;
    int pidx = side * 65536 + b * 2048 + pi;
    float bd = fminf(__uint_as_float(part[pidx]), __uint_as_float(part[131072 + pidx]));
    u32 bits = __float_as_uint(bd);
    u32 bi = bits & 0x7FFu;                            // global q index
    float dmin = __uint_as_float(bits & 0xFFFFF800u);  // truncated min d'
    float p0 = praw[3 * pi], p1 = praw[3 * pi + 1], p2 = praw[3 * pi + 2];
    if (p0 + p1 + p2 != 0.f) {
      contrib += dmin + p0 * p0 + p1 * p1 + p2 * p2;
      cnt += 1.f;
      atomicOr(&hitlds[bi >> 5], 1u << (bi & 31));
    }
    float q0 = qraw[3 * pi], q1 = qraw[3 * pi + 1], q2 = qraw[3 * pi + 2];
    if (q0 + q1 + q2 != 0.f) qcnt += 1.f;
  }

  for (int o = 32; o > 0; o >>= 1) {
    contrib += __shfl_down(contrib, o, 64);
    cnt += __shfl_down(cnt, o, 64);
    qcnt += __shfl_down(qcnt, o, 64);
  }
  if (lane == 0) { redc[w] = contrib; redn[w] = cnt; redq[w] = qcnt; }
  __syncthreads();

  if (tid < 64) {  // wave 0: popcount bitmask + final combine
    float h = (float)__popc(hitlds[tid]);
    for (int o = 32; o > 0; o >>= 1) h += __shfl_down(h, o, 64);
    if (tid == 0) {
      float s = 0.f, n = 0.f, nq = 0.f;
#pragma unroll
      for (int i = 0; i < 16; ++i) { s += redc[i]; n += redn[i]; nq += redq[i]; }
      float cdt = s / n;       // this side's mean-min-distance term
      float hqt = h / nq;      // hit fraction of q indices
      const float inv = 1.f / (float)BB;
      atomicAdd(out + 1, cdt * inv);
      atomicAdd(out + 2 + side, hqt * inv);
      atomicAdd(out + 0, (cdt - 1e-4f * hqt) * inv);
    }
  }
}

extern "C" void kernel_launch(void* const* d_in, const int* in_sizes, int n_in,
                              void* d_out, int out_size, void* d_ws, size_t ws_size,
                              hipStream_t stream) {
  const float* x = (const float*)d_in[0];
  const float* y = (const float*)d_in[1];
  float* out = (float*)d_out;
  char* ws = (char*)d_ws;

  // ws layout: [0, 1MB) part: 2 qc x 131072 u32 embedded (d|idx).
  // Fully written by nn_kernel before merge3 reads it; no memset needed.
  u32* part = (u32*)ws;

  nn_kernel<<<1024, 512, 0, stream>>>(x, y, part, out);
  merge3_kernel<<<64, 1024, 0, stream>>>(x, y, part, out);
}